// Round 1
// baseline (64.906 us; speedup 1.0000x reference)
//
#include <hip/hip_runtime.h>
#include <math.h>

// SemiConvModel: max-plus 1xK conv (K=15, parabolic weights), reduced over
// C_IN=3, broadcast to C_OUT=16 identical channels.
// out[b,c,h,w] = max_n( max_cin x[b,cin,h,w+n-7] + w[n] ),  w[n] = -(n-7)^2/(4*scale)

#define BB   16
#define CIN  3
#define HH   512
#define WW   512
#define COUT 16
#define KK   15
#define HALF 7
// padded row: 7 + 512 + 7 = 526, rounded to 528 for float4 tail reads

__global__ __launch_bounds__(128) void semiconv_kernel(
    const float* __restrict__ x, const float* __restrict__ scale_p,
    float* __restrict__ out)
{
    __shared__ __align__(16) float m[528];
    const int t   = threadIdx.x;
    const int row = blockIdx.x;      // 0 .. B*H-1
    const int b   = row >> 9;        // / 512
    const int h   = row & 511;

    const float inv4s = 0.25f / scale_p[0];

    // ---- stage channel-max padded row into LDS (x read exactly once) ----
    const float* xr = x + ((size_t)(b * CIN) * HH + h) * WW;
    #pragma unroll
    for (int jj = 0; jj < 528; jj += 128) {
        int j = jj + t;
        if (jj + 128 <= 528 || j < 528) {
            int src = j - HALF;
            float v = -INFINITY;
            if (src >= 0 && src < WW) {
                float v0 = xr[src];
                float v1 = xr[(size_t)HH * WW + src];
                float v2 = xr[2 * (size_t)HH * WW + src];
                v = fmaxf(fmaxf(v0, v1), v2);
            }
            m[j] = v;
        }
    }
    __syncthreads();

    // ---- parabolic weights (exact for scale=1: integer^2 * 0.25) ----
    float wt[KK];
    #pragma unroll
    for (int n = 0; n < KK; ++n) {
        float z = (float)(n - HALF);
        wt[n] = -(z * z) * inv4s;
    }

    // ---- each thread: 4 consecutive outputs from 20 LDS floats ----
    const int w0 = t << 2;           // 0..508
    float v[20];
    #pragma unroll
    for (int k = 0; k < 5; ++k) {
        float4 a = *(const float4*)&m[w0 + 4 * k];
        v[4 * k + 0] = a.x; v[4 * k + 1] = a.y;
        v[4 * k + 2] = a.z; v[4 * k + 3] = a.w;
    }

    float res[4];
    #pragma unroll
    for (int i = 0; i < 4; ++i) {
        float best = v[i] + wt[0];
        #pragma unroll
        for (int n = 1; n < KK; ++n)
            best = fmaxf(best, v[i + n] + wt[n]);
        res[i] = best;
    }
    float4 r;
    r.x = res[0]; r.y = res[1]; r.z = res[2]; r.w = res[3];

    // ---- write identical value to all 16 output channels (float4 stores) ----
    float* ob = out + ((size_t)b * COUT * HH + h) * WW + w0;
    #pragma unroll
    for (int c = 0; c < COUT; ++c) {
        *(float4*)(ob + (size_t)c * HH * WW) = r;
    }
}

extern "C" void kernel_launch(void* const* d_in, const int* in_sizes, int n_in,
                              void* d_out, int out_size, void* d_ws, size_t ws_size,
                              hipStream_t stream) {
    const float* x     = (const float*)d_in[0];
    const float* scale = (const float*)d_in[1];
    float* out         = (float*)d_out;

    dim3 grid(BB * HH);   // 8192 blocks, one per (b,h) row
    dim3 block(128);
    hipLaunchKernelGGL(semiconv_kernel, grid, block, 0, stream, x, scale, out);
}

// Round 3
// 56.372 us; speedup vs baseline: 1.1514x; 1.1514x over previous
//
#include <hip/hip_runtime.h>
#include <math.h>

// SemiConvModel: max-plus 1xK conv (K=15, parabolic weights), reduced over
// C_IN=3, broadcast to C_OUT=16 identical channels.
// out[b,c,h,w] = max_n( max_cin x[b,cin,h,w+n-7] + w[n] ),  w[n] = -(n-7)^2/(4*scale)
//
// Round 3: round-2 design with the nontemporal store fixed to use a clang
// native vector type (ext_vector_type) instead of HIP_vector_type.

#define BB   16
#define CIN  3
#define HH   512
#define WW   512
#define COUT 16
#define KK   15
#define HALF 7
#define ROWS 4          // rows per block
#define TPB  512        // threads per block

typedef float floatx4 __attribute__((ext_vector_type(4)));

// LDS row layout: index p in [8, 520) holds xmax[p-8]; p in [0,8) and
// [520,528) are -inf pads. Left pad of 8 (not 7) keeps float4 stores aligned.

__global__ __launch_bounds__(TPB) void semiconv_kernel(
    const float* __restrict__ x, const float* __restrict__ scale_p,
    float* __restrict__ out)
{
    __shared__ __align__(16) float m[ROWS][528];
    const int t  = threadIdx.x;
    const int g  = blockIdx.x;        // 0 .. B*H/ROWS - 1  (2048)
    const int b  = g >> 7;            // 128 row-groups per batch
    const int h0 = (g & 127) << 2;    // first row of the group

    const float inv4s = 0.25f / scale_p[0];

    // ---- -inf pads: 4 rows x 16 pad slots = 64 entries ----
    if (t < 64) {
        int r = t >> 4;
        int q = t & 15;
        int p = (q < 8) ? q : (512 + q);   // 0..7 and 520..527
        m[r][p] = -INFINITY;
    }

    // ---- vectorized channel-max staging: 4 rows x 128 float4 = 512 threads ----
    {
        int r = t >> 7;                // row within group
        int i = t & 127;               // float4 index within row
        const floatx4* xr = (const floatx4*)(x + ((size_t)(b * CIN) * HH + (h0 + r)) * (size_t)WW) + i;
        const size_t cs = (size_t)HH * WW / 4;   // channel stride in float4s
        floatx4 a0 = xr[0];
        floatx4 a1 = xr[cs];
        floatx4 a2 = xr[2 * cs];
        floatx4 mx;
        mx.x = fmaxf(fmaxf(a0.x, a1.x), a2.x);
        mx.y = fmaxf(fmaxf(a0.y, a1.y), a2.y);
        mx.z = fmaxf(fmaxf(a0.z, a1.z), a2.z);
        mx.w = fmaxf(fmaxf(a0.w, a1.w), a2.w);
        *(floatx4*)&m[r][8 + 4 * i] = mx;
    }
    __syncthreads();

    // ---- parabolic weights (exact for scale=1: integer^2 * 0.25) ----
    float wt[KK];
    #pragma unroll
    for (int n = 0; n < KK; ++n) {
        float z = (float)(n - HALF);
        wt[n] = -(z * z) * inv4s;
    }

    // ---- compute: thread -> (row r, 4 outputs at w0) ----
    const int r  = t >> 7;
    const int w0 = (t & 127) << 2;
    float v[20];
    #pragma unroll
    for (int k = 0; k < 5; ++k) {
        floatx4 a = *(const floatx4*)&m[r][w0 + 4 * k];
        v[4 * k + 0] = a.x; v[4 * k + 1] = a.y;
        v[4 * k + 2] = a.z; v[4 * k + 3] = a.w;
    }
    // output w0+i uses input w0+i+n-7 -> LDS p = w0 + (i+n+1)
    float res[4];
    #pragma unroll
    for (int i = 0; i < 4; ++i) {
        float best = v[i + 1] + wt[0];
        #pragma unroll
        for (int n = 1; n < KK; ++n)
            best = fmaxf(best, v[i + n + 1] + wt[n]);
        res[i] = best;
    }
    floatx4 rv;
    rv.x = res[0]; rv.y = res[1]; rv.z = res[2]; rv.w = res[3];

    // ---- nontemporal stores: 16 channels, 8KB contiguous per channel/block ----
    float* ob = out + ((size_t)(b * COUT) * HH + (h0 + r)) * (size_t)WW + w0;
    #pragma unroll
    for (int c = 0; c < COUT; ++c) {
        __builtin_nontemporal_store(rv, (floatx4*)(ob + (size_t)c * HH * WW));
    }
}

extern "C" void kernel_launch(void* const* d_in, const int* in_sizes, int n_in,
                              void* d_out, int out_size, void* d_ws, size_t ws_size,
                              hipStream_t stream) {
    const float* x     = (const float*)d_in[0];
    const float* scale = (const float*)d_in[1];
    float* out         = (float*)d_out;

    dim3 grid(BB * HH / ROWS);   // 2048 blocks
    dim3 block(TPB);
    hipLaunchKernelGGL(semiconv_kernel, grid, block, 0, stream, x, scale, out);
}